// Round 3
// baseline (561.402 us; speedup 1.0000x reference)
//
#include <hip/hip_runtime.h>
#include <hip/hip_bf16.h>

// MultiLayerGATv2 — Round 3:
//  * gat_ln: bf16 xl gather (half bytes), 32 lanes/node, reg-buffered esrc via
//    shfl, 2-way unrolled edge loop (load ILP), fused LN+ELU+residual.
//  * gemm_in: 16 rows/block, ds_read_b128, wave-parallel LN (no bank conflicts).
//  * gemm_xlxr: 16 rows/block, ds_read_b128, writes xl as bf16 (RNE).
//  * CSR scan: hierarchical shfl scan.

#define NN 50000
#define EE 800000
#define EP (EE + NN)
#define IN_DIM 256
#define HID 128
#define SLOPE 0.2f
#define LN_EPS 1e-5f

__device__ __forceinline__ float bf2f(unsigned int u16) {
    union { unsigned int i; float f; } c; c.i = u16 << 16; return c.f;
}
__device__ __forceinline__ float bf2f_hi(unsigned int packed) {
    union { unsigned int i; float f; } c; c.i = packed & 0xffff0000u; return c.f;
}
__device__ __forceinline__ unsigned short f2bf(float f) {
    union { float f; unsigned int i; } c; c.f = f;
    unsigned int r = (c.i + 0x7fffu + ((c.i >> 16) & 1u)) >> 16;   // RNE
    return (unsigned short)r;
}

// ---------------- input GEMM + LN + ReLU (16 rows / 128-thread block) --------
__global__ void gemm_in_ln_relu(const float* __restrict__ x,
                                const float* __restrict__ W,
                                const float* __restrict__ b,
                                const float* __restrict__ g,
                                const float* __restrict__ bb,
                                float* __restrict__ h) {
    __shared__ float xs[16][IN_DIM];          // 16 KB
    __shared__ float stats[16][2];
    const int tid = threadIdx.x;
    const size_t node0 = (size_t)blockIdx.x * 16;

    const float4* xv = (const float4*)(x + node0 * IN_DIM);
    float4* xsv = (float4*)&xs[0][0];
#pragma unroll
    for (int i = 0; i < 8; i++) xsv[tid + i * 128] = xv[tid + i * 128];
    __syncthreads();

    float acc[16];
#pragma unroll
    for (int r = 0; r < 16; r++) acc[r] = 0.f;
    for (int k = 0; k < IN_DIM; k += 4) {
        const float w0 = W[(k + 0) * HID + tid];
        const float w1 = W[(k + 1) * HID + tid];
        const float w2 = W[(k + 2) * HID + tid];
        const float w3 = W[(k + 3) * HID + tid];
#pragma unroll
        for (int r = 0; r < 16; r++) {
            const float4 xr4 = *(const float4*)&xs[r][k];
            acc[r] += xr4.x * w0 + xr4.y * w1 + xr4.z * w2 + xr4.w * w3;
        }
    }
    const float bv = b[tid];
#pragma unroll
    for (int r = 0; r < 16; r++) acc[r] += bv;

    // ---- wave-parallel LayerNorm over the 16 rows ----
    __syncthreads();                          // xs reads done
    float* lnbuf = &xs[0][0];                 // reuse as [16][128]
#pragma unroll
    for (int r = 0; r < 16; r++) lnbuf[r * HID + tid] = acc[r];
    __syncthreads();
    {
        const int wv = tid >> 6, lane = tid & 63;
#pragma unroll
        for (int rr = 0; rr < 8; rr++) {
            const int r = wv * 8 + rr;
            const float a = lnbuf[r * HID + lane];
            const float c = lnbuf[r * HID + lane + 64];
            float s1 = a + c, s2 = a * a + c * c;
#pragma unroll
            for (int off = 1; off < 64; off <<= 1) {
                s1 += __shfl_xor(s1, off);
                s2 += __shfl_xor(s2, off);
            }
            if (lane == 0) {
                const float mu = s1 / (float)HID;
                stats[r][0] = mu;
                stats[r][1] = rsqrtf(s2 / (float)HID - mu * mu + LN_EPS);
            }
        }
    }
    __syncthreads();
    const float gv = g[tid], bbv = bb[tid];
#pragma unroll
    for (int r = 0; r < 16; r++) {
        const float v = (acc[r] - stats[r][0]) * stats[r][1] * gv + bbv;
        h[(node0 + r) * HID + tid] = fmaxf(v, 0.f);
    }
}

// ---------------- dual GEMM: xl(bf16) = h@Wl, xr(f32) = h@Wr ----------------
__global__ void gemm_xlxr(const float* __restrict__ h,
                          const float* __restrict__ Wl,
                          const float* __restrict__ Wr,
                          unsigned short* __restrict__ xl,
                          float* __restrict__ xr) {
    __shared__ float hs[16][HID];             // 8 KB
    const int tid = threadIdx.x;
    const size_t node0 = (size_t)blockIdx.x * 16;

    const float4* hv = (const float4*)(h + node0 * HID);
    float4* hsv = (float4*)&hs[0][0];
#pragma unroll
    for (int i = 0; i < 4; i++) hsv[tid + i * 128] = hv[tid + i * 128];
    __syncthreads();

    float aL[16], aR[16];
#pragma unroll
    for (int r = 0; r < 16; r++) { aL[r] = 0.f; aR[r] = 0.f; }
    for (int k = 0; k < HID; k += 4) {
        const float l0 = Wl[(k + 0) * HID + tid];
        const float l1 = Wl[(k + 1) * HID + tid];
        const float l2 = Wl[(k + 2) * HID + tid];
        const float l3 = Wl[(k + 3) * HID + tid];
        const float r0 = Wr[(k + 0) * HID + tid];
        const float r1 = Wr[(k + 1) * HID + tid];
        const float r2 = Wr[(k + 2) * HID + tid];
        const float r3 = Wr[(k + 3) * HID + tid];
#pragma unroll
        for (int r = 0; r < 16; r++) {
            const float4 h4 = *(const float4*)&hs[r][k];
            aL[r] += h4.x * l0 + h4.y * l1 + h4.z * l2 + h4.w * l3;
            aR[r] += h4.x * r0 + h4.y * r1 + h4.z * r2 + h4.w * r3;
        }
    }
#pragma unroll
    for (int r = 0; r < 16; r++) {
        xl[(node0 + r) * HID + tid] = f2bf(aL[r]);
        xr[(node0 + r) * HID + tid] = aR[r];
    }
}

// ---------------- CSR build ----------------
__global__ void dst_hist(const int* __restrict__ ei, int* __restrict__ cnt) {
    const long e = (long)blockIdx.x * 256 + threadIdx.x;
    if (e >= EP) return;
    const int d = (e < EE) ? ei[EE + e] : (int)(e - EE);
    atomicAdd(&cnt[d], 1);
}

__global__ void scan_rowptr(const int* __restrict__ cnt, int* __restrict__ rowptr) {
    const int PER = 49;                        // ceil(50000/1024)
    const int t = threadIdx.x;
    const int start = t * PER;
    const int end = min(start + PER, NN);
    int local = 0;
    for (int i = start; i < end; i++) local += cnt[i];

    const int lane = t & 63, wv = t >> 6;
    int v = local;
#pragma unroll
    for (int off = 1; off < 64; off <<= 1) {
        const int u = __shfl_up(v, off);
        if (lane >= off) v += u;
    }
    __shared__ int wsum[16];
    if (lane == 63) wsum[wv] = v;
    __syncthreads();
    if (t < 16) {
        int s = wsum[t];
#pragma unroll
        for (int off = 1; off < 16; off <<= 1) {
            const int u = __shfl_up(s, off);
            if (t >= off) s += u;
        }
        wsum[t] = s;
    }
    __syncthreads();
    const int waveoff = (wv > 0) ? wsum[wv - 1] : 0;
    int run = waveoff + v - local;             // exclusive prefix
    for (int i = start; i < end; i++) { rowptr[i] = run; run += cnt[i]; }
    if (t == 1023) rowptr[NN] = waveoff + v;   // grand total == EP
}

__global__ void csr_scatter(const int* __restrict__ ei,
                            const int* __restrict__ rowptr,
                            int* __restrict__ fill,
                            int* __restrict__ esrc) {
    const long e = (long)blockIdx.x * 256 + threadIdx.x;
    if (e >= EP) return;
    int s, d;
    if (e < EE) { s = ei[e]; d = ei[EE + e]; }
    else        { s = d = (int)(e - EE); }
    const int pos = atomicAdd(&fill[d], 1);
    esrc[rowptr[d] + pos] = s;
}

// ---------------- fused GAT conv + LN + ELU + residual ----------------
// 32 lanes per dst node (lane holds 4 features), 8 nodes per 256-thr block.
// esrc buffered 32-wide in a register, broadcast via shfl.
__global__ void gat_ln(const unsigned short* __restrict__ xl,
                       const float* __restrict__ xr,
                       const float* __restrict__ att,
                       const int* __restrict__ rowptr,
                       const int* __restrict__ esrc,
                       const float* __restrict__ g,
                       const float* __restrict__ b,
                       const float* __restrict__ hres,
                       float* __restrict__ dest) {
    const int tid = threadIdx.x;
    const int lane32 = tid & 31;
    const int gbase = tid & 32;                // shfl base of this 32-group in wave
    const int node = blockIdx.x * 8 + (tid >> 5);
    if (node >= NN) return;
    const int f0 = lane32 * 4;

    const float4 xrv = *(const float4*)(xr + (size_t)node * HID + f0);
    const float4 atv = *(const float4*)(att + f0);
    const int beg = rowptr[node];
    const int deg = rowptr[node + 1] - beg;    // >= 1

    float4 acc; acc.x = acc.y = acc.z = acc.w = 0.f;
    float z = 0.f;

#define PROC(S) do {                                                        \
        const uint2 raw = *(const uint2*)(xl + (size_t)(S) * HID + f0);     \
        const float m0 = bf2f(raw.x & 0xffffu);                             \
        const float m1 = bf2f_hi(raw.x);                                    \
        const float m2 = bf2f(raw.y & 0xffffu);                             \
        const float m3 = bf2f_hi(raw.y);                                    \
        float e0 = m0 + xrv.x; e0 = e0 > 0.f ? e0 : SLOPE * e0;             \
        float e1 = m1 + xrv.y; e1 = e1 > 0.f ? e1 : SLOPE * e1;             \
        float e2 = m2 + xrv.z; e2 = e2 > 0.f ? e2 : SLOPE * e2;             \
        float e3 = m3 + xrv.w; e3 = e3 > 0.f ? e3 : SLOPE * e3;             \
        float v = e0 * atv.x + e1 * atv.y + e2 * atv.z + e3 * atv.w;        \
        v += __shfl_xor(v, 1);                                              \
        v += __shfl_xor(v, 2);                                              \
        v += __shfl_xor(v, 4);          /* 8-lane head group */             \
        const float a = __expf(v);                                          \
        z += a;                                                             \
        acc.x += a * m0; acc.y += a * m1; acc.z += a * m2; acc.w += a * m3; \
    } while (0)

    int sbuf = (lane32 < deg) ? esrc[beg + lane32] : 0;
    int i = 0;
    while (true) {
        const int lim = min(deg, (i & ~31) + 32);
        for (; i + 2 <= lim; i += 2) {
            const int s0 = __shfl(sbuf, gbase + (i & 31));
            const int s1 = __shfl(sbuf, gbase + ((i + 1) & 31));
            PROC(s0);
            PROC(s1);
        }
        if (i < lim) {
            const int s0 = __shfl(sbuf, gbase + (i & 31));
            PROC(s0);
            i++;
        }
        if (i >= deg) break;
        sbuf = (i + lane32 < deg) ? esrc[beg + i + lane32] : 0;
    }
#undef PROC

    const float inv = 1.f / z;
    const float ox = acc.x * inv, oy = acc.y * inv, oz = acc.z * inv, ow = acc.w * inv;

    // LayerNorm across the node's 32 lanes
    float s1 = ox + oy + oz + ow;
    float s2 = ox * ox + oy * oy + oz * oz + ow * ow;
#pragma unroll
    for (int off = 1; off < 32; off <<= 1) {
        s1 += __shfl_xor(s1, off);
        s2 += __shfl_xor(s2, off);
    }
    const float mu = s1 / (float)HID;
    const float rstd = rsqrtf(s2 / (float)HID - mu * mu + LN_EPS);
    const float4 gv = *(const float4*)(g + f0);
    const float4 bv = *(const float4*)(b + f0);
    float nx = (ox - mu) * rstd * gv.x + bv.x;
    float ny = (oy - mu) * rstd * gv.y + bv.y;
    float nz = (oz - mu) * rstd * gv.z + bv.z;
    float nw = (ow - mu) * rstd * gv.w + bv.w;
    nx = nx > 0.f ? nx : expm1f(nx);
    ny = ny > 0.f ? ny : expm1f(ny);
    nz = nz > 0.f ? nz : expm1f(nz);
    nw = nw > 0.f ? nw : expm1f(nw);
    const float4 hv = *(const float4*)(hres + (size_t)node * HID + f0);
    float4 res;
    res.x = hv.x + nx; res.y = hv.y + ny; res.z = hv.z + nz; res.w = hv.w + nw;
    *(float4*)(dest + (size_t)node * HID + f0) = res;
}

extern "C" void kernel_launch(void* const* d_in, const int* in_sizes, int n_in,
                              void* d_out, int out_size, void* d_ws, size_t ws_size,
                              hipStream_t stream) {
    const float* x       = (const float*)d_in[0];
    const float* W_in    = (const float*)d_in[1];
    const float* b_in    = (const float*)d_in[2];
    const float* ln_in_g = (const float*)d_in[3];
    const float* ln_in_b = (const float*)d_in[4];
    const float* Wl      = (const float*)d_in[5];
    const float* Wr      = (const float*)d_in[6];
    const float* att     = (const float*)d_in[7];
    const float* ln_g    = (const float*)d_in[8];
    const float* ln_b    = (const float*)d_in[9];
    const int*   ei      = (const int*)d_in[10];
    float* out = (float*)d_out;

    float* h  = (float*)d_ws;
    float* xr = h + (size_t)NN * HID;
    unsigned short* xlb = (unsigned short*)(xr + (size_t)NN * HID);
    int* cnt    = (int*)(xlb + (size_t)NN * HID);
    int* fill   = cnt + NN;
    int* rowptr = fill + NN;
    int* esrc   = rowptr + (NN + 1);

    hipMemsetAsync(cnt, 0, 2 * NN * sizeof(int), stream);
    const int eblocks = (EP + 255) / 256;
    dst_hist<<<eblocks, 256, 0, stream>>>(ei, cnt);
    scan_rowptr<<<1, 1024, 0, stream>>>(cnt, rowptr);
    csr_scatter<<<eblocks, 256, 0, stream>>>(ei, rowptr, fill, esrc);

    gemm_in_ln_relu<<<NN / 16, 128, 0, stream>>>(x, W_in, b_in, ln_in_g, ln_in_b, h);

    for (int l = 0; l < 2; l++) {
        gemm_xlxr<<<NN / 16, 128, 0, stream>>>(h, Wl + (size_t)l * HID * HID,
                                               Wr + (size_t)l * HID * HID, xlb, xr);
        gat_ln<<<(NN + 7) / 8, 256, 0, stream>>>(xlb, xr, att + (size_t)l * HID,
                                                 rowptr, esrc,
                                                 ln_g + (size_t)l * HID,
                                                 ln_b + (size_t)l * HID,
                                                 h, (l == 0) ? h : out);
    }
}

// Round 4
// 304.108 us; speedup vs baseline: 1.8461x; 1.8461x over previous
//
#include <hip/hip_runtime.h>
#include <hip/hip_bf16.h>

// MultiLayerGATv2 — Round 4: all GEMMs moved to bf16 MFMA (16x16x32).
//  * prep_weights: one-time conversion of W_in/Wl/Wr to bf16 in B-fragment
//    order (lane=col, 8 contiguous k per lane) into workspace.
//  * gemm kernels: 64 rows/block (4 waves x 16 rows), fragment-ordered
//    weights staged to LDS (64 KB, b128 conflict-free), A-frags loaded
//    directly from global (h kept as parallel bf16 copy).
//  * gemm_in fuses bias+LN+ReLU on C-fragments (16-lane shfl row reduce).
//  * gat_ln unchanged, plus optional bf16 dest for the next layer's GEMM.

#define NN 50000
#define EE 800000
#define EP (EE + NN)
#define IN_DIM 256
#define HID 128
#define SLOPE 0.2f
#define LN_EPS 1e-5f

typedef short s8v __attribute__((ext_vector_type(8)));   // 8 bf16 (4 VGPR)
typedef float f4v __attribute__((ext_vector_type(4)));   // MFMA C/D

__device__ __forceinline__ float bf2f(unsigned int u16) {
    union { unsigned int i; float f; } c; c.i = u16 << 16; return c.f;
}
__device__ __forceinline__ float bf2f_hi(unsigned int packed) {
    union { unsigned int i; float f; } c; c.i = packed & 0xffff0000u; return c.f;
}
__device__ __forceinline__ unsigned short f2bf(float f) {
    union { float f; unsigned int i; } c; c.f = f;
    unsigned int r = (c.i + 0x7fffu + ((c.i >> 16) & 1u)) >> 16;   // RNE
    return (unsigned short)r;
}

// ---------------- weight prep: fp32 [K][128] -> bf16 fragment slots ----------
// slot s (16 B) holds 8 bf16: W[kbase..kbase+7][n], kbase = (s>>9)*32 + ((s>>7)&3)*8,
// n = s&127.  Regions: [0,4096) W_in; then 2048-slot blocks l0Wl,l0Wr,l1Wl,l1Wr.
__global__ void prep_weights(const float* __restrict__ Win,
                             const float* __restrict__ Wl,
                             const float* __restrict__ Wr,
                             float4* __restrict__ wp) {
    const int sid = blockIdx.x * 256 + threadIdx.x;    // grid 48*256 = 12288
    const float* W;
    int slot;
    if (sid < 4096) { W = Win; slot = sid; }
    else {
        const int m = (sid - 4096) >> 11;
        slot = (sid - 4096) & 2047;
        W = (m == 0) ? Wl : (m == 1) ? Wr : (m == 2) ? (Wl + 16384) : (Wr + 16384);
    }
    const int n = slot & 127;
    const int kbase = (slot >> 9) * 32 + ((slot >> 7) & 3) * 8;
    unsigned short o[8];
#pragma unroll
    for (int j = 0; j < 8; j++) o[j] = f2bf(W[(size_t)(kbase + j) * 128 + n]);
    wp[sid] = *(const float4*)o;
}

// ---------------- input GEMM (x@W_in) + bias + LN + ReLU, MFMA ----------------
// 256 thr = 4 waves; 64 rows/block; K=256 (8 k-steps), N=128 (8 n-tiles).
__global__ __launch_bounds__(256) void gemm_in_mfma(
        const float* __restrict__ x,
        const float4* __restrict__ wp,        // 4096 slots, fragment order
        const float* __restrict__ bin,
        const float* __restrict__ g,
        const float* __restrict__ bb,
        float* __restrict__ h,
        unsigned short* __restrict__ hb) {
    __shared__ s8v wlds[4096];                // 64 KB
    const int tid = threadIdx.x;
    const int wv = tid >> 6, lane = tid & 63;
    const int l15 = lane & 15, kseg = lane >> 4;
    const int row0 = blockIdx.x * 64 + wv * 16;
    const int arow = row0 + l15;
    const int r = (arow < NN) ? arow : 0;

    // A fragments: 8 k-steps x 8 bf16 (converted from fp32 x)
    s8v afrag[8];
#pragma unroll
    for (int ks = 0; ks < 8; ks++) {
        const float* ap = x + (size_t)r * IN_DIM + ks * 32 + kseg * 8;
        const float4 a0 = *(const float4*)ap;
        const float4 a1 = *(const float4*)(ap + 4);
        unsigned short t[8] = { f2bf(a0.x), f2bf(a0.y), f2bf(a0.z), f2bf(a0.w),
                                f2bf(a1.x), f2bf(a1.y), f2bf(a1.z), f2bf(a1.w) };
        afrag[ks] = *(const s8v*)t;
    }

    // stage fragment-ordered weights to LDS (coalesced, conflict-free)
    const float4* wp4 = wp;
#pragma unroll
    for (int i = 0; i < 16; i++) {
        const int idx = i * 256 + tid;
        ((float4*)wlds)[idx] = wp4[idx];
    }
    __syncthreads();

    f4v acc[8];
#pragma unroll
    for (int nb = 0; nb < 8; nb++) acc[nb] = (f4v){0.f, 0.f, 0.f, 0.f};
#pragma unroll
    for (int ks = 0; ks < 8; ks++) {
#pragma unroll
        for (int nb = 0; nb < 8; nb++) {
            const s8v bfrag = wlds[(ks * 4 + kseg) * 128 + nb * 16 + l15];
            acc[nb] = __builtin_amdgcn_mfma_f32_16x16x32_bf16(afrag[ks], bfrag, acc[nb], 0, 0, 0);
        }
    }

    // bias + LN + ReLU on C fragments.
    // lane holds rows {4*kseg+reg}, cols {nb*16 + l15}.
    float binv[8], gv[8], bbv[8];
#pragma unroll
    for (int nb = 0; nb < 8; nb++) {
        const int col = nb * 16 + l15;
        binv[nb] = bin[col]; gv[nb] = g[col]; bbv[nb] = bb[col];
    }
    float s1[4] = {0.f, 0.f, 0.f, 0.f}, s2[4] = {0.f, 0.f, 0.f, 0.f};
#pragma unroll
    for (int nb = 0; nb < 8; nb++)
#pragma unroll
        for (int reg = 0; reg < 4; reg++) {
            const float t = acc[nb][reg] + binv[nb];
            acc[nb][reg] = t;
            s1[reg] += t; s2[reg] += t * t;
        }
#pragma unroll
    for (int off = 1; off < 16; off <<= 1)
#pragma unroll
        for (int reg = 0; reg < 4; reg++) {
            s1[reg] += __shfl_xor(s1[reg], off);
            s2[reg] += __shfl_xor(s2[reg], off);
        }
    float mu[4], rstd[4];
#pragma unroll
    for (int reg = 0; reg < 4; reg++) {
        mu[reg] = s1[reg] / (float)HID;
        rstd[reg] = rsqrtf(s2[reg] / (float)HID - mu[reg] * mu[reg] + LN_EPS);
    }
    const int rbase = row0 + 4 * kseg;
#pragma unroll
    for (int reg = 0; reg < 4; reg++) {
        const int grow = rbase + reg;
        if (grow >= NN) continue;
#pragma unroll
        for (int nb = 0; nb < 8; nb++) {
            const int col = nb * 16 + l15;
            float v = (acc[nb][reg] - mu[reg]) * rstd[reg] * gv[nb] + bbv[nb];
            v = fmaxf(v, 0.f);
            h[(size_t)grow * HID + col] = v;
            hb[(size_t)grow * HID + col] = f2bf(v);
        }
    }
}

// ---------------- dual GEMM (h@Wl -> xl bf16, h@Wr -> xr f32), MFMA ----------
__global__ __launch_bounds__(256) void gemm_xlxr_mfma(
        const unsigned short* __restrict__ hb,
        const float4* __restrict__ wp,        // 4096 slots: Wl 0..2047, Wr 2048..4095
        unsigned short* __restrict__ xl,
        float* __restrict__ xr) {
    __shared__ s8v wlds[4096];                // 64 KB
    const int tid = threadIdx.x;
    const int wv = tid >> 6, lane = tid & 63;
    const int l15 = lane & 15, kseg = lane >> 4;
    const int row0 = blockIdx.x * 64 + wv * 16;
    const int arow = row0 + l15;
    const int r = (arow < NN) ? arow : 0;

    s8v afrag[4];
#pragma unroll
    for (int ks = 0; ks < 4; ks++)
        afrag[ks] = *(const s8v*)(hb + (size_t)r * HID + ks * 32 + kseg * 8);

#pragma unroll
    for (int i = 0; i < 16; i++) {
        const int idx = i * 256 + tid;
        ((float4*)wlds)[idx] = wp[idx];
    }
    __syncthreads();

    f4v accL[8], accR[8];
#pragma unroll
    for (int nb = 0; nb < 8; nb++) {
        accL[nb] = (f4v){0.f, 0.f, 0.f, 0.f};
        accR[nb] = (f4v){0.f, 0.f, 0.f, 0.f};
    }
#pragma unroll
    for (int ks = 0; ks < 4; ks++) {
#pragma unroll
        for (int nb = 0; nb < 8; nb++) {
            const s8v bL = wlds[(ks * 4 + kseg) * 128 + nb * 16 + l15];
            accL[nb] = __builtin_amdgcn_mfma_f32_16x16x32_bf16(afrag[ks], bL, accL[nb], 0, 0, 0);
            const s8v bR = wlds[2048 + (ks * 4 + kseg) * 128 + nb * 16 + l15];
            accR[nb] = __builtin_amdgcn_mfma_f32_16x16x32_bf16(afrag[ks], bR, accR[nb], 0, 0, 0);
        }
    }

    const int rbase = row0 + 4 * kseg;
#pragma unroll
    for (int reg = 0; reg < 4; reg++) {
        const int grow = rbase + reg;
        if (grow >= NN) continue;
#pragma unroll
        for (int nb = 0; nb < 8; nb++) {
            const int col = nb * 16 + l15;
            xl[(size_t)grow * HID + col] = f2bf(accL[nb][reg]);
            xr[(size_t)grow * HID + col] = accR[nb][reg];
        }
    }
}

// ---------------- CSR build ----------------
__global__ void dst_hist(const int* __restrict__ ei, int* __restrict__ cnt) {
    const long e = (long)blockIdx.x * 256 + threadIdx.x;
    if (e >= EP) return;
    const int d = (e < EE) ? ei[EE + e] : (int)(e - EE);
    atomicAdd(&cnt[d], 1);
}

__global__ void scan_rowptr(const int* __restrict__ cnt, int* __restrict__ rowptr) {
    const int PER = 49;
    const int t = threadIdx.x;
    const int start = t * PER;
    const int end = min(start + PER, NN);
    int local = 0;
    for (int i = start; i < end; i++) local += cnt[i];

    const int lane = t & 63, wv = t >> 6;
    int v = local;
#pragma unroll
    for (int off = 1; off < 64; off <<= 1) {
        const int u = __shfl_up(v, off);
        if (lane >= off) v += u;
    }
    __shared__ int wsum[16];
    if (lane == 63) wsum[wv] = v;
    __syncthreads();
    if (t < 16) {
        int s = wsum[t];
#pragma unroll
        for (int off = 1; off < 16; off <<= 1) {
            const int u = __shfl_up(s, off);
            if (t >= off) s += u;
        }
        wsum[t] = s;
    }
    __syncthreads();
    const int waveoff = (wv > 0) ? wsum[wv - 1] : 0;
    int run = waveoff + v - local;
    for (int i = start; i < end; i++) { rowptr[i] = run; run += cnt[i]; }
    if (t == 1023) rowptr[NN] = waveoff + v;
}

__global__ void csr_scatter(const int* __restrict__ ei,
                            const int* __restrict__ rowptr,
                            int* __restrict__ fill,
                            int* __restrict__ esrc) {
    const long e = (long)blockIdx.x * 256 + threadIdx.x;
    if (e >= EP) return;
    int s, d;
    if (e < EE) { s = ei[e]; d = ei[EE + e]; }
    else        { s = d = (int)(e - EE); }
    const int pos = atomicAdd(&fill[d], 1);
    esrc[rowptr[d] + pos] = s;
}

// ---------------- fused GAT conv + LN + ELU + residual ----------------
__global__ void gat_ln(const unsigned short* __restrict__ xl,
                       const float* __restrict__ xr,
                       const float* __restrict__ att,
                       const int* __restrict__ rowptr,
                       const int* __restrict__ esrc,
                       const float* __restrict__ g,
                       const float* __restrict__ b,
                       const float* __restrict__ hres,
                       float* __restrict__ dest,
                       unsigned short* __restrict__ destb) {
    const int tid = threadIdx.x;
    const int lane32 = tid & 31;
    const int gbase = tid & 32;
    const int node = blockIdx.x * 8 + (tid >> 5);
    if (node >= NN) return;
    const int f0 = lane32 * 4;

    const float4 xrv = *(const float4*)(xr + (size_t)node * HID + f0);
    const float4 atv = *(const float4*)(att + f0);
    const int beg = rowptr[node];
    const int deg = rowptr[node + 1] - beg;

    float4 acc; acc.x = acc.y = acc.z = acc.w = 0.f;
    float z = 0.f;

#define PROC(S) do {                                                        \
        const uint2 raw = *(const uint2*)(xl + (size_t)(S) * HID + f0);     \
        const float m0 = bf2f(raw.x & 0xffffu);                             \
        const float m1 = bf2f_hi(raw.x);                                    \
        const float m2 = bf2f(raw.y & 0xffffu);                             \
        const float m3 = bf2f_hi(raw.y);                                    \
        float e0 = m0 + xrv.x; e0 = e0 > 0.f ? e0 : SLOPE * e0;             \
        float e1 = m1 + xrv.y; e1 = e1 > 0.f ? e1 : SLOPE * e1;             \
        float e2 = m2 + xrv.z; e2 = e2 > 0.f ? e2 : SLOPE * e2;             \
        float e3 = m3 + xrv.w; e3 = e3 > 0.f ? e3 : SLOPE * e3;             \
        float v = e0 * atv.x + e1 * atv.y + e2 * atv.z + e3 * atv.w;        \
        v += __shfl_xor(v, 1);                                              \
        v += __shfl_xor(v, 2);                                              \
        v += __shfl_xor(v, 4);                                              \
        const float a = __expf(v);                                          \
        z += a;                                                             \
        acc.x += a * m0; acc.y += a * m1; acc.z += a * m2; acc.w += a * m3; \
    } while (0)

    int sbuf = (lane32 < deg) ? esrc[beg + lane32] : 0;
    int i = 0;
    while (true) {
        const int lim = min(deg, (i & ~31) + 32);
        for (; i + 2 <= lim; i += 2) {
            const int s0 = __shfl(sbuf, gbase + (i & 31));
            const int s1 = __shfl(sbuf, gbase + ((i + 1) & 31));
            PROC(s0);
            PROC(s1);
        }
        if (i < lim) {
            const int s0 = __shfl(sbuf, gbase + (i & 31));
            PROC(s0);
            i++;
        }
        if (i >= deg) break;
        sbuf = (i + lane32 < deg) ? esrc[beg + i + lane32] : 0;
    }
#undef PROC

    const float inv = 1.f / z;
    const float ox = acc.x * inv, oy = acc.y * inv, oz = acc.z * inv, ow = acc.w * inv;

    float s1 = ox + oy + oz + ow;
    float s2 = ox * ox + oy * oy + oz * oz + ow * ow;
#pragma unroll
    for (int off = 1; off < 32; off <<= 1) {
        s1 += __shfl_xor(s1, off);
        s2 += __shfl_xor(s2, off);
    }
    const float mu = s1 / (float)HID;
    const float rstd = rsqrtf(s2 / (float)HID - mu * mu + LN_EPS);
    const float4 gv = *(const float4*)(g + f0);
    const float4 bv = *(const float4*)(b + f0);
    float nx = (ox - mu) * rstd * gv.x + bv.x;
    float ny = (oy - mu) * rstd * gv.y + bv.y;
    float nz = (oz - mu) * rstd * gv.z + bv.z;
    float nw = (ow - mu) * rstd * gv.w + bv.w;
    nx = nx > 0.f ? nx : expm1f(nx);
    ny = ny > 0.f ? ny : expm1f(ny);
    nz = nz > 0.f ? nz : expm1f(nz);
    nw = nw > 0.f ? nw : expm1f(nw);
    const float4 hv = *(const float4*)(hres + (size_t)node * HID + f0);
    float4 res;
    res.x = hv.x + nx; res.y = hv.y + ny; res.z = hv.z + nz; res.w = hv.w + nw;
    *(float4*)(dest + (size_t)node * HID + f0) = res;
    if (destb) {
        unsigned short* db = destb + (size_t)node * HID + f0;
        db[0] = f2bf(res.x); db[1] = f2bf(res.y);
        db[2] = f2bf(res.z); db[3] = f2bf(res.w);
    }
}

extern "C" void kernel_launch(void* const* d_in, const int* in_sizes, int n_in,
                              void* d_out, int out_size, void* d_ws, size_t ws_size,
                              hipStream_t stream) {
    const float* x       = (const float*)d_in[0];
    const float* W_in    = (const float*)d_in[1];
    const float* b_in    = (const float*)d_in[2];
    const float* ln_in_g = (const float*)d_in[3];
    const float* ln_in_b = (const float*)d_in[4];
    const float* Wl      = (const float*)d_in[5];
    const float* Wr      = (const float*)d_in[6];
    const float* att     = (const float*)d_in[7];
    const float* ln_g    = (const float*)d_in[8];
    const float* ln_b    = (const float*)d_in[9];
    const int*   ei      = (const int*)d_in[10];
    float* out = (float*)d_out;

    float* h  = (float*)d_ws;                                  // NN*128 f32
    float* xr = h + (size_t)NN * HID;                          // NN*128 f32
    unsigned short* hb  = (unsigned short*)(xr + (size_t)NN * HID);   // NN*128 bf16
    unsigned short* xlb = hb + (size_t)NN * HID;               // NN*128 bf16
    float4* wp = (float4*)(xlb + (size_t)NN * HID);            // 12288 slots
    int* cnt    = (int*)(wp + 12288);
    int* fill   = cnt + NN;
    int* rowptr = fill + NN;
    int* esrc   = rowptr + (NN + 1);

    prep_weights<<<48, 256, 0, stream>>>(W_in, Wl, Wr, wp);

    hipMemsetAsync(cnt, 0, 2 * NN * sizeof(int), stream);
    const int eblocks = (EP + 255) / 256;
    dst_hist<<<eblocks, 256, 0, stream>>>(ei, cnt);
    scan_rowptr<<<1, 1024, 0, stream>>>(cnt, rowptr);
    csr_scatter<<<eblocks, 256, 0, stream>>>(ei, rowptr, fill, esrc);

    const int mblocks = (NN + 63) / 64;
    gemm_in_mfma<<<mblocks, 256, 0, stream>>>(x, wp, b_in, ln_in_g, ln_in_b, h, hb);

    for (int l = 0; l < 2; l++) {
        gemm_xlxr_mfma<<<mblocks, 256, 0, stream>>>(hb, wp + 4096 + l * 4096, xlb, xr);
        gat_ln<<<(NN + 7) / 8, 256, 0, stream>>>(xlb, xr, att + (size_t)l * HID,
                                                 rowptr, esrc,
                                                 ln_g + (size_t)l * HID,
                                                 ln_b + (size_t)l * HID,
                                                 h, (l == 0) ? h : out,
                                                 (l == 0) ? hb : (unsigned short*)nullptr);
    }
}

// Round 5
// 236.302 us; speedup vs baseline: 2.3758x; 1.2869x over previous
//
#include <hip/hip_runtime.h>
#include <hip/hip_bf16.h>

// MultiLayerGATv2 — Round 5: replace the single-block 75us rowptr scan with a
// 3-stage parallel scan (block-reduce -> scan partials -> block-scan+offset).
// Everything else unchanged from Round 4 (MFMA GEMMs, fused gather-GAT).

#define NN 50000
#define EE 800000
#define EP (EE + NN)
#define IN_DIM 256
#define HID 128
#define SLOPE 0.2f
#define LN_EPS 1e-5f
#define NB 196          // ceil(NN / 256)

typedef short s8v __attribute__((ext_vector_type(8)));   // 8 bf16 (4 VGPR)
typedef float f4v __attribute__((ext_vector_type(4)));   // MFMA C/D

__device__ __forceinline__ float bf2f(unsigned int u16) {
    union { unsigned int i; float f; } c; c.i = u16 << 16; return c.f;
}
__device__ __forceinline__ float bf2f_hi(unsigned int packed) {
    union { unsigned int i; float f; } c; c.i = packed & 0xffff0000u; return c.f;
}
__device__ __forceinline__ unsigned short f2bf(float f) {
    union { float f; unsigned int i; } c; c.f = f;
    unsigned int r = (c.i + 0x7fffu + ((c.i >> 16) & 1u)) >> 16;   // RNE
    return (unsigned short)r;
}

// ---------------- weight prep (unchanged) ----------------
__global__ void prep_weights(const float* __restrict__ Win,
                             const float* __restrict__ Wl,
                             const float* __restrict__ Wr,
                             float4* __restrict__ wp) {
    const int sid = blockIdx.x * 256 + threadIdx.x;    // grid 48*256 = 12288
    const float* W;
    int slot;
    if (sid < 4096) { W = Win; slot = sid; }
    else {
        const int m = (sid - 4096) >> 11;
        slot = (sid - 4096) & 2047;
        W = (m == 0) ? Wl : (m == 1) ? Wr : (m == 2) ? (Wl + 16384) : (Wr + 16384);
    }
    const int n = slot & 127;
    const int kbase = (slot >> 9) * 32 + ((slot >> 7) & 3) * 8;
    unsigned short o[8];
#pragma unroll
    for (int j = 0; j < 8; j++) o[j] = f2bf(W[(size_t)(kbase + j) * 128 + n]);
    wp[sid] = *(const float4*)o;
}

// ---------------- input GEMM + bias + LN + ReLU, MFMA (unchanged) ------------
__global__ __launch_bounds__(256) void gemm_in_mfma(
        const float* __restrict__ x,
        const float4* __restrict__ wp,
        const float* __restrict__ bin,
        const float* __restrict__ g,
        const float* __restrict__ bb,
        float* __restrict__ h,
        unsigned short* __restrict__ hb) {
    __shared__ s8v wlds[4096];                // 64 KB
    const int tid = threadIdx.x;
    const int wv = tid >> 6, lane = tid & 63;
    const int l15 = lane & 15, kseg = lane >> 4;
    const int row0 = blockIdx.x * 64 + wv * 16;
    const int arow = row0 + l15;
    const int r = (arow < NN) ? arow : 0;

    s8v afrag[8];
#pragma unroll
    for (int ks = 0; ks < 8; ks++) {
        const float* ap = x + (size_t)r * IN_DIM + ks * 32 + kseg * 8;
        const float4 a0 = *(const float4*)ap;
        const float4 a1 = *(const float4*)(ap + 4);
        unsigned short t[8] = { f2bf(a0.x), f2bf(a0.y), f2bf(a0.z), f2bf(a0.w),
                                f2bf(a1.x), f2bf(a1.y), f2bf(a1.z), f2bf(a1.w) };
        afrag[ks] = *(const s8v*)t;
    }

#pragma unroll
    for (int i = 0; i < 16; i++) {
        const int idx = i * 256 + tid;
        ((float4*)wlds)[idx] = wp[idx];
    }
    __syncthreads();

    f4v acc[8];
#pragma unroll
    for (int nb = 0; nb < 8; nb++) acc[nb] = (f4v){0.f, 0.f, 0.f, 0.f};
#pragma unroll
    for (int ks = 0; ks < 8; ks++) {
#pragma unroll
        for (int nb = 0; nb < 8; nb++) {
            const s8v bfrag = wlds[(ks * 4 + kseg) * 128 + nb * 16 + l15];
            acc[nb] = __builtin_amdgcn_mfma_f32_16x16x32_bf16(afrag[ks], bfrag, acc[nb], 0, 0, 0);
        }
    }

    float binv[8], gv[8], bbv[8];
#pragma unroll
    for (int nb = 0; nb < 8; nb++) {
        const int col = nb * 16 + l15;
        binv[nb] = bin[col]; gv[nb] = g[col]; bbv[nb] = bb[col];
    }
    float s1[4] = {0.f, 0.f, 0.f, 0.f}, s2[4] = {0.f, 0.f, 0.f, 0.f};
#pragma unroll
    for (int nb = 0; nb < 8; nb++)
#pragma unroll
        for (int reg = 0; reg < 4; reg++) {
            const float t = acc[nb][reg] + binv[nb];
            acc[nb][reg] = t;
            s1[reg] += t; s2[reg] += t * t;
        }
#pragma unroll
    for (int off = 1; off < 16; off <<= 1)
#pragma unroll
        for (int reg = 0; reg < 4; reg++) {
            s1[reg] += __shfl_xor(s1[reg], off);
            s2[reg] += __shfl_xor(s2[reg], off);
        }
    float mu[4], rstd[4];
#pragma unroll
    for (int reg = 0; reg < 4; reg++) {
        mu[reg] = s1[reg] / (float)HID;
        rstd[reg] = rsqrtf(s2[reg] / (float)HID - mu[reg] * mu[reg] + LN_EPS);
    }
    const int rbase = row0 + 4 * kseg;
#pragma unroll
    for (int reg = 0; reg < 4; reg++) {
        const int grow = rbase + reg;
        if (grow >= NN) continue;
#pragma unroll
        for (int nb = 0; nb < 8; nb++) {
            const int col = nb * 16 + l15;
            float v = (acc[nb][reg] - mu[reg]) * rstd[reg] * gv[nb] + bbv[nb];
            v = fmaxf(v, 0.f);
            h[(size_t)grow * HID + col] = v;
            hb[(size_t)grow * HID + col] = f2bf(v);
        }
    }
}

// ---------------- dual GEMM, MFMA (unchanged) ----------------
__global__ __launch_bounds__(256) void gemm_xlxr_mfma(
        const unsigned short* __restrict__ hb,
        const float4* __restrict__ wp,
        unsigned short* __restrict__ xl,
        float* __restrict__ xr) {
    __shared__ s8v wlds[4096];                // 64 KB
    const int tid = threadIdx.x;
    const int wv = tid >> 6, lane = tid & 63;
    const int l15 = lane & 15, kseg = lane >> 4;
    const int row0 = blockIdx.x * 64 + wv * 16;
    const int arow = row0 + l15;
    const int r = (arow < NN) ? arow : 0;

    s8v afrag[4];
#pragma unroll
    for (int ks = 0; ks < 4; ks++)
        afrag[ks] = *(const s8v*)(hb + (size_t)r * HID + ks * 32 + kseg * 8);

#pragma unroll
    for (int i = 0; i < 16; i++) {
        const int idx = i * 256 + tid;
        ((float4*)wlds)[idx] = wp[idx];
    }
    __syncthreads();

    f4v accL[8], accR[8];
#pragma unroll
    for (int nb = 0; nb < 8; nb++) {
        accL[nb] = (f4v){0.f, 0.f, 0.f, 0.f};
        accR[nb] = (f4v){0.f, 0.f, 0.f, 0.f};
    }
#pragma unroll
    for (int ks = 0; ks < 4; ks++) {
#pragma unroll
        for (int nb = 0; nb < 8; nb++) {
            const s8v bL = wlds[(ks * 4 + kseg) * 128 + nb * 16 + l15];
            accL[nb] = __builtin_amdgcn_mfma_f32_16x16x32_bf16(afrag[ks], bL, accL[nb], 0, 0, 0);
            const s8v bR = wlds[2048 + (ks * 4 + kseg) * 128 + nb * 16 + l15];
            accR[nb] = __builtin_amdgcn_mfma_f32_16x16x32_bf16(afrag[ks], bR, accR[nb], 0, 0, 0);
        }
    }

    const int rbase = row0 + 4 * kseg;
#pragma unroll
    for (int reg = 0; reg < 4; reg++) {
        const int grow = rbase + reg;
        if (grow >= NN) continue;
#pragma unroll
        for (int nb = 0; nb < 8; nb++) {
            const int col = nb * 16 + l15;
            xl[(size_t)grow * HID + col] = f2bf(accL[nb][reg]);
            xr[(size_t)grow * HID + col] = accR[nb][reg];
        }
    }
}

// ---------------- CSR build: hist + 3-stage parallel scan + scatter ----------
__global__ void dst_hist(const int* __restrict__ ei, int* __restrict__ cnt) {
    const long e = (long)blockIdx.x * 256 + threadIdx.x;
    if (e >= EP) return;
    const int d = (e < EE) ? ei[EE + e] : (int)(e - EE);
    atomicAdd(&cnt[d], 1);
}

// stage 1: per-256-chunk totals
__global__ void scan_bsum(const int* __restrict__ cnt, int* __restrict__ bsum) {
    const int tid = threadIdx.x;
    const int i = blockIdx.x * 256 + tid;
    int v = (i < NN) ? cnt[i] : 0;
#pragma unroll
    for (int off = 1; off < 64; off <<= 1) v += __shfl_xor(v, off);
    __shared__ int ws[4];
    if ((tid & 63) == 0) ws[tid >> 6] = v;
    __syncthreads();
    if (tid == 0) bsum[blockIdx.x] = ws[0] + ws[1] + ws[2] + ws[3];
}

// stage 2: exclusive scan of NB partials (single block, 256 thr)
__global__ void scan_bpre(const int* __restrict__ bsum, int* __restrict__ bpre) {
    const int t = threadIdx.x;
    const int lane = t & 63, wv = t >> 6;
    const int v = (t < NB) ? bsum[t] : 0;
    int s = v;
#pragma unroll
    for (int off = 1; off < 64; off <<= 1) {
        const int u = __shfl_up(s, off);
        if (lane >= off) s += u;
    }
    __shared__ int wt[4];
    if (lane == 63) wt[wv] = s;
    __syncthreads();
    int add = 0;
    for (int w = 0; w < wv; w++) add += wt[w];
    if (t < NB) bpre[t] = s + add - v;     // exclusive
}

// stage 3: local exclusive scan + chunk offset -> rowptr
__global__ void scan_rowptr(const int* __restrict__ cnt,
                            const int* __restrict__ bpre,
                            int* __restrict__ rowptr) {
    const int tid = threadIdx.x;
    const int lane = tid & 63, wv = tid >> 6;
    const int i = blockIdx.x * 256 + tid;
    const int v = (i < NN) ? cnt[i] : 0;
    int s = v;
#pragma unroll
    for (int off = 1; off < 64; off <<= 1) {
        const int u = __shfl_up(s, off);
        if (lane >= off) s += u;
    }
    __shared__ int wt[4];
    if (lane == 63) wt[wv] = s;
    __syncthreads();
    int add = bpre[blockIdx.x];
    for (int w = 0; w < wv; w++) add += wt[w];
    const int excl = s + add - v;
    if (i < NN) rowptr[i] = excl;
    if (i == NN - 1) rowptr[NN] = excl + v;   // == EP
}

__global__ void csr_scatter(const int* __restrict__ ei,
                            const int* __restrict__ rowptr,
                            int* __restrict__ fill,
                            int* __restrict__ esrc) {
    const long e = (long)blockIdx.x * 256 + threadIdx.x;
    if (e >= EP) return;
    int s, d;
    if (e < EE) { s = ei[e]; d = ei[EE + e]; }
    else        { s = d = (int)(e - EE); }
    const int pos = atomicAdd(&fill[d], 1);
    esrc[rowptr[d] + pos] = s;
}

// ---------------- fused GAT conv + LN + ELU + residual (unchanged) ----------
__global__ void gat_ln(const unsigned short* __restrict__ xl,
                       const float* __restrict__ xr,
                       const float* __restrict__ att,
                       const int* __restrict__ rowptr,
                       const int* __restrict__ esrc,
                       const float* __restrict__ g,
                       const float* __restrict__ b,
                       const float* __restrict__ hres,
                       float* __restrict__ dest,
                       unsigned short* __restrict__ destb) {
    const int tid = threadIdx.x;
    const int lane32 = tid & 31;
    const int gbase = tid & 32;
    const int node = blockIdx.x * 8 + (tid >> 5);
    if (node >= NN) return;
    const int f0 = lane32 * 4;

    const float4 xrv = *(const float4*)(xr + (size_t)node * HID + f0);
    const float4 atv = *(const float4*)(att + f0);
    const int beg = rowptr[node];
    const int deg = rowptr[node + 1] - beg;

    float4 acc; acc.x = acc.y = acc.z = acc.w = 0.f;
    float z = 0.f;

#define PROC(S) do {                                                        \
        const uint2 raw = *(const uint2*)(xl + (size_t)(S) * HID + f0);     \
        const float m0 = bf2f(raw.x & 0xffffu);                             \
        const float m1 = bf2f_hi(raw.x);                                    \
        const float m2 = bf2f(raw.y & 0xffffu);                             \
        const float m3 = bf2f_hi(raw.y);                                    \
        float e0 = m0 + xrv.x; e0 = e0 > 0.f ? e0 : SLOPE * e0;             \
        float e1 = m1 + xrv.y; e1 = e1 > 0.f ? e1 : SLOPE * e1;             \
        float e2 = m2 + xrv.z; e2 = e2 > 0.f ? e2 : SLOPE * e2;             \
        float e3 = m3 + xrv.w; e3 = e3 > 0.f ? e3 : SLOPE * e3;             \
        float v = e0 * atv.x + e1 * atv.y + e2 * atv.z + e3 * atv.w;        \
        v += __shfl_xor(v, 1);                                              \
        v += __shfl_xor(v, 2);                                              \
        v += __shfl_xor(v, 4);                                              \
        const float a = __expf(v);                                          \
        z += a;                                                             \
        acc.x += a * m0; acc.y += a * m1; acc.z += a * m2; acc.w += a * m3; \
    } while (0)

    int sbuf = (lane32 < deg) ? esrc[beg + lane32] : 0;
    int i = 0;
    while (true) {
        const int lim = min(deg, (i & ~31) + 32);
        for (; i + 2 <= lim; i += 2) {
            const int s0 = __shfl(sbuf, gbase + (i & 31));
            const int s1 = __shfl(sbuf, gbase + ((i + 1) & 31));
            PROC(s0);
            PROC(s1);
        }
        if (i < lim) {
            const int s0 = __shfl(sbuf, gbase + (i & 31));
            PROC(s0);
            i++;
        }
        if (i >= deg) break;
        sbuf = (i + lane32 < deg) ? esrc[beg + i + lane32] : 0;
    }
#undef PROC

    const float inv = 1.f / z;
    const float ox = acc.x * inv, oy = acc.y * inv, oz = acc.z * inv, ow = acc.w * inv;

    float s1 = ox + oy + oz + ow;
    float s2 = ox * ox + oy * oy + oz * oz + ow * ow;
#pragma unroll
    for (int off = 1; off < 32; off <<= 1) {
        s1 += __shfl_xor(s1, off);
        s2 += __shfl_xor(s2, off);
    }
    const float mu = s1 / (float)HID;
    const float rstd = rsqrtf(s2 / (float)HID - mu * mu + LN_EPS);
    const float4 gv = *(const float4*)(g + f0);
    const float4 bv = *(const float4*)(b + f0);
    float nx = (ox - mu) * rstd * gv.x + bv.x;
    float ny = (oy - mu) * rstd * gv.y + bv.y;
    float nz = (oz - mu) * rstd * gv.z + bv.z;
    float nw = (ow - mu) * rstd * gv.w + bv.w;
    nx = nx > 0.f ? nx : expm1f(nx);
    ny = ny > 0.f ? ny : expm1f(ny);
    nz = nz > 0.f ? nz : expm1f(nz);
    nw = nw > 0.f ? nw : expm1f(nw);
    const float4 hv = *(const float4*)(hres + (size_t)node * HID + f0);
    float4 res;
    res.x = hv.x + nx; res.y = hv.y + ny; res.z = hv.z + nz; res.w = hv.w + nw;
    *(float4*)(dest + (size_t)node * HID + f0) = res;
    if (destb) {
        unsigned short* db = destb + (size_t)node * HID + f0;
        db[0] = f2bf(res.x); db[1] = f2bf(res.y);
        db[2] = f2bf(res.z); db[3] = f2bf(res.w);
    }
}

extern "C" void kernel_launch(void* const* d_in, const int* in_sizes, int n_in,
                              void* d_out, int out_size, void* d_ws, size_t ws_size,
                              hipStream_t stream) {
    const float* x       = (const float*)d_in[0];
    const float* W_in    = (const float*)d_in[1];
    const float* b_in    = (const float*)d_in[2];
    const float* ln_in_g = (const float*)d_in[3];
    const float* ln_in_b = (const float*)d_in[4];
    const float* Wl      = (const float*)d_in[5];
    const float* Wr      = (const float*)d_in[6];
    const float* att     = (const float*)d_in[7];
    const float* ln_g    = (const float*)d_in[8];
    const float* ln_b    = (const float*)d_in[9];
    const int*   ei      = (const int*)d_in[10];
    float* out = (float*)d_out;

    float* h  = (float*)d_ws;                                  // NN*128 f32
    float* xr = h + (size_t)NN * HID;                          // NN*128 f32
    unsigned short* hb  = (unsigned short*)(xr + (size_t)NN * HID);   // NN*128 bf16
    unsigned short* xlb = hb + (size_t)NN * HID;               // NN*128 bf16
    float4* wp = (float4*)(xlb + (size_t)NN * HID);            // 12288 slots
    int* cnt    = (int*)(wp + 12288);
    int* fill   = cnt + NN;
    int* rowptr = fill + NN;
    int* bsum   = rowptr + (NN + 1);
    int* bpre   = bsum + NB;
    int* esrc   = bpre + NB;

    prep_weights<<<48, 256, 0, stream>>>(W_in, Wl, Wr, wp);

    hipMemsetAsync(cnt, 0, 2 * NN * sizeof(int), stream);
    const int eblocks = (EP + 255) / 256;
    dst_hist<<<eblocks, 256, 0, stream>>>(ei, cnt);
    scan_bsum<<<NB, 256, 0, stream>>>(cnt, bsum);
    scan_bpre<<<1, 256, 0, stream>>>(bsum, bpre);
    scan_rowptr<<<NB, 256, 0, stream>>>(cnt, bpre, rowptr);
    csr_scatter<<<eblocks, 256, 0, stream>>>(ei, rowptr, fill, esrc);

    const int mblocks = (NN + 63) / 64;
    gemm_in_mfma<<<mblocks, 256, 0, stream>>>(x, wp, b_in, ln_in_g, ln_in_b, h, hb);

    for (int l = 0; l < 2; l++) {
        gemm_xlxr_mfma<<<mblocks, 256, 0, stream>>>(hb, wp + 4096 + l * 4096, xlb, xr);
        gat_ln<<<(NN + 7) / 8, 256, 0, stream>>>(xlb, xr, att + (size_t)l * HID,
                                                 rowptr, esrc,
                                                 ln_g + (size_t)l * HID,
                                                 ln_b + (size_t)l * HID,
                                                 h, (l == 0) ? h : out,
                                                 (l == 0) ? hb : (unsigned short*)nullptr);
    }
}

// Round 6
// 232.202 us; speedup vs baseline: 2.4177x; 1.0177x over previous
//
#include <hip/hip_runtime.h>
#include <hip/hip_bf16.h>

// MultiLayerGATv2 — Round 6: gat_ln VALU diet.
//  leaky_relu folded into the attention dot:  att·leaky(s) = (0.6att)·s + (0.4att)·|s|
//  (|s| is a free VOP3 input modifier on v_fma_f32) — 5 ops/feature -> 3.
//  Everything else unchanged from Round 5.

#define NN 50000
#define EE 800000
#define EP (EE + NN)
#define IN_DIM 256
#define HID 128
#define SLOPE 0.2f
#define LN_EPS 1e-5f
#define NB 196          // ceil(NN / 256)

typedef short s8v __attribute__((ext_vector_type(8)));   // 8 bf16 (4 VGPR)
typedef float f4v __attribute__((ext_vector_type(4)));   // MFMA C/D

__device__ __forceinline__ float u2f(unsigned int u) {
    union { unsigned int i; float f; } c; c.i = u; return c.f;
}
__device__ __forceinline__ unsigned short f2bf(float f) {
    union { float f; unsigned int i; } c; c.f = f;
    unsigned int r = (c.i + 0x7fffu + ((c.i >> 16) & 1u)) >> 16;   // RNE
    return (unsigned short)r;
}

// ---------------- weight prep (unchanged) ----------------
__global__ void prep_weights(const float* __restrict__ Win,
                             const float* __restrict__ Wl,
                             const float* __restrict__ Wr,
                             float4* __restrict__ wp) {
    const int sid = blockIdx.x * 256 + threadIdx.x;    // grid 48*256 = 12288
    const float* W;
    int slot;
    if (sid < 4096) { W = Win; slot = sid; }
    else {
        const int m = (sid - 4096) >> 11;
        slot = (sid - 4096) & 2047;
        W = (m == 0) ? Wl : (m == 1) ? Wr : (m == 2) ? (Wl + 16384) : (Wr + 16384);
    }
    const int n = slot & 127;
    const int kbase = (slot >> 9) * 32 + ((slot >> 7) & 3) * 8;
    unsigned short o[8];
#pragma unroll
    for (int j = 0; j < 8; j++) o[j] = f2bf(W[(size_t)(kbase + j) * 128 + n]);
    wp[sid] = *(const float4*)o;
}

// ---------------- input GEMM + bias + LN + ReLU, MFMA (unchanged) ------------
__global__ __launch_bounds__(256) void gemm_in_mfma(
        const float* __restrict__ x,
        const float4* __restrict__ wp,
        const float* __restrict__ bin,
        const float* __restrict__ g,
        const float* __restrict__ bb,
        float* __restrict__ h,
        unsigned short* __restrict__ hb) {
    __shared__ s8v wlds[4096];                // 64 KB
    const int tid = threadIdx.x;
    const int wv = tid >> 6, lane = tid & 63;
    const int l15 = lane & 15, kseg = lane >> 4;
    const int row0 = blockIdx.x * 64 + wv * 16;
    const int arow = row0 + l15;
    const int r = (arow < NN) ? arow : 0;

    s8v afrag[8];
#pragma unroll
    for (int ks = 0; ks < 8; ks++) {
        const float* ap = x + (size_t)r * IN_DIM + ks * 32 + kseg * 8;
        const float4 a0 = *(const float4*)ap;
        const float4 a1 = *(const float4*)(ap + 4);
        unsigned short t[8] = { f2bf(a0.x), f2bf(a0.y), f2bf(a0.z), f2bf(a0.w),
                                f2bf(a1.x), f2bf(a1.y), f2bf(a1.z), f2bf(a1.w) };
        afrag[ks] = *(const s8v*)t;
    }

#pragma unroll
    for (int i = 0; i < 16; i++) {
        const int idx = i * 256 + tid;
        ((float4*)wlds)[idx] = wp[idx];
    }
    __syncthreads();

    f4v acc[8];
#pragma unroll
    for (int nb = 0; nb < 8; nb++) acc[nb] = (f4v){0.f, 0.f, 0.f, 0.f};
#pragma unroll
    for (int ks = 0; ks < 8; ks++) {
#pragma unroll
        for (int nb = 0; nb < 8; nb++) {
            const s8v bfrag = wlds[(ks * 4 + kseg) * 128 + nb * 16 + l15];
            acc[nb] = __builtin_amdgcn_mfma_f32_16x16x32_bf16(afrag[ks], bfrag, acc[nb], 0, 0, 0);
        }
    }

    float binv[8], gv[8], bbv[8];
#pragma unroll
    for (int nb = 0; nb < 8; nb++) {
        const int col = nb * 16 + l15;
        binv[nb] = bin[col]; gv[nb] = g[col]; bbv[nb] = bb[col];
    }
    float s1[4] = {0.f, 0.f, 0.f, 0.f}, s2[4] = {0.f, 0.f, 0.f, 0.f};
#pragma unroll
    for (int nb = 0; nb < 8; nb++)
#pragma unroll
        for (int reg = 0; reg < 4; reg++) {
            const float t = acc[nb][reg] + binv[nb];
            acc[nb][reg] = t;
            s1[reg] += t; s2[reg] += t * t;
        }
#pragma unroll
    for (int off = 1; off < 16; off <<= 1)
#pragma unroll
        for (int reg = 0; reg < 4; reg++) {
            s1[reg] += __shfl_xor(s1[reg], off);
            s2[reg] += __shfl_xor(s2[reg], off);
        }
    float mu[4], rstd[4];
#pragma unroll
    for (int reg = 0; reg < 4; reg++) {
        mu[reg] = s1[reg] / (float)HID;
        rstd[reg] = rsqrtf(s2[reg] / (float)HID - mu[reg] * mu[reg] + LN_EPS);
    }
    const int rbase = row0 + 4 * kseg;
#pragma unroll
    for (int reg = 0; reg < 4; reg++) {
        const int grow = rbase + reg;
        if (grow >= NN) continue;
#pragma unroll
        for (int nb = 0; nb < 8; nb++) {
            const int col = nb * 16 + l15;
            float v = (acc[nb][reg] - mu[reg]) * rstd[reg] * gv[nb] + bbv[nb];
            v = fmaxf(v, 0.f);
            h[(size_t)grow * HID + col] = v;
            hb[(size_t)grow * HID + col] = f2bf(v);
        }
    }
}

// ---------------- dual GEMM, MFMA (unchanged) ----------------
__global__ __launch_bounds__(256) void gemm_xlxr_mfma(
        const unsigned short* __restrict__ hb,
        const float4* __restrict__ wp,
        unsigned short* __restrict__ xl,
        float* __restrict__ xr) {
    __shared__ s8v wlds[4096];                // 64 KB
    const int tid = threadIdx.x;
    const int wv = tid >> 6, lane = tid & 63;
    const int l15 = lane & 15, kseg = lane >> 4;
    const int row0 = blockIdx.x * 64 + wv * 16;
    const int arow = row0 + l15;
    const int r = (arow < NN) ? arow : 0;

    s8v afrag[4];
#pragma unroll
    for (int ks = 0; ks < 4; ks++)
        afrag[ks] = *(const s8v*)(hb + (size_t)r * HID + ks * 32 + kseg * 8);

#pragma unroll
    for (int i = 0; i < 16; i++) {
        const int idx = i * 256 + tid;
        ((float4*)wlds)[idx] = wp[idx];
    }
    __syncthreads();

    f4v accL[8], accR[8];
#pragma unroll
    for (int nb = 0; nb < 8; nb++) {
        accL[nb] = (f4v){0.f, 0.f, 0.f, 0.f};
        accR[nb] = (f4v){0.f, 0.f, 0.f, 0.f};
    }
#pragma unroll
    for (int ks = 0; ks < 4; ks++) {
#pragma unroll
        for (int nb = 0; nb < 8; nb++) {
            const s8v bL = wlds[(ks * 4 + kseg) * 128 + nb * 16 + l15];
            accL[nb] = __builtin_amdgcn_mfma_f32_16x16x32_bf16(afrag[ks], bL, accL[nb], 0, 0, 0);
            const s8v bR = wlds[2048 + (ks * 4 + kseg) * 128 + nb * 16 + l15];
            accR[nb] = __builtin_amdgcn_mfma_f32_16x16x32_bf16(afrag[ks], bR, accR[nb], 0, 0, 0);
        }
    }

    const int rbase = row0 + 4 * kseg;
#pragma unroll
    for (int reg = 0; reg < 4; reg++) {
        const int grow = rbase + reg;
        if (grow >= NN) continue;
#pragma unroll
        for (int nb = 0; nb < 8; nb++) {
            const int col = nb * 16 + l15;
            xl[(size_t)grow * HID + col] = f2bf(accL[nb][reg]);
            xr[(size_t)grow * HID + col] = accR[nb][reg];
        }
    }
}

// ---------------- CSR build (unchanged) ----------------
__global__ void dst_hist(const int* __restrict__ ei, int* __restrict__ cnt) {
    const long e = (long)blockIdx.x * 256 + threadIdx.x;
    if (e >= EP) return;
    const int d = (e < EE) ? ei[EE + e] : (int)(e - EE);
    atomicAdd(&cnt[d], 1);
}

__global__ void scan_bsum(const int* __restrict__ cnt, int* __restrict__ bsum) {
    const int tid = threadIdx.x;
    const int i = blockIdx.x * 256 + tid;
    int v = (i < NN) ? cnt[i] : 0;
#pragma unroll
    for (int off = 1; off < 64; off <<= 1) v += __shfl_xor(v, off);
    __shared__ int ws[4];
    if ((tid & 63) == 0) ws[tid >> 6] = v;
    __syncthreads();
    if (tid == 0) bsum[blockIdx.x] = ws[0] + ws[1] + ws[2] + ws[3];
}

__global__ void scan_bpre(const int* __restrict__ bsum, int* __restrict__ bpre) {
    const int t = threadIdx.x;
    const int lane = t & 63, wv = t >> 6;
    const int v = (t < NB) ? bsum[t] : 0;
    int s = v;
#pragma unroll
    for (int off = 1; off < 64; off <<= 1) {
        const int u = __shfl_up(s, off);
        if (lane >= off) s += u;
    }
    __shared__ int wt[4];
    if (lane == 63) wt[wv] = s;
    __syncthreads();
    int add = 0;
    for (int w = 0; w < wv; w++) add += wt[w];
    if (t < NB) bpre[t] = s + add - v;     // exclusive
}

__global__ void scan_rowptr(const int* __restrict__ cnt,
                            const int* __restrict__ bpre,
                            int* __restrict__ rowptr) {
    const int tid = threadIdx.x;
    const int lane = tid & 63, wv = tid >> 6;
    const int i = blockIdx.x * 256 + tid;
    const int v = (i < NN) ? cnt[i] : 0;
    int s = v;
#pragma unroll
    for (int off = 1; off < 64; off <<= 1) {
        const int u = __shfl_up(s, off);
        if (lane >= off) s += u;
    }
    __shared__ int wt[4];
    if (lane == 63) wt[wv] = s;
    __syncthreads();
    int add = bpre[blockIdx.x];
    for (int w = 0; w < wv; w++) add += wt[w];
    const int excl = s + add - v;
    if (i < NN) rowptr[i] = excl;
    if (i == NN - 1) rowptr[NN] = excl + v;   // == EP
}

__global__ void csr_scatter(const int* __restrict__ ei,
                            const int* __restrict__ rowptr,
                            int* __restrict__ fill,
                            int* __restrict__ esrc) {
    const long e = (long)blockIdx.x * 256 + threadIdx.x;
    if (e >= EP) return;
    int s, d;
    if (e < EE) { s = ei[e]; d = ei[EE + e]; }
    else        { s = d = (int)(e - EE); }
    const int pos = atomicAdd(&fill[d], 1);
    esrc[rowptr[d] + pos] = s;
}

// ---------------- fused GAT conv + LN + ELU + residual ----------------
// att·leaky(s) = (0.6att)·s + (0.4att)·|s|  (|s| free via VOP3 abs modifier)
__global__ __launch_bounds__(256) void gat_ln(
                       const unsigned short* __restrict__ xl,
                       const float* __restrict__ xr,
                       const float* __restrict__ att,
                       const int* __restrict__ rowptr,
                       const int* __restrict__ esrc,
                       const float* __restrict__ g,
                       const float* __restrict__ b,
                       const float* __restrict__ hres,
                       float* __restrict__ dest,
                       unsigned short* __restrict__ destb) {
    const int tid = threadIdx.x;
    const int lane32 = tid & 31;
    const int gbase = tid & 32;
    const int node = blockIdx.x * 8 + (tid >> 5);
    if (node >= NN) return;
    const int f0 = lane32 * 4;

    const float4 xrv = *(const float4*)(xr + (size_t)node * HID + f0);
    const float4 atv = *(const float4*)(att + f0);
    float4 a06, a04;
    a06.x = 0.6f * atv.x; a06.y = 0.6f * atv.y; a06.z = 0.6f * atv.z; a06.w = 0.6f * atv.w;
    a04.x = 0.4f * atv.x; a04.y = 0.4f * atv.y; a04.z = 0.4f * atv.z; a04.w = 0.4f * atv.w;
    const int beg = rowptr[node];
    const int deg = rowptr[node + 1] - beg;

    float4 acc; acc.x = acc.y = acc.z = acc.w = 0.f;
    float z = 0.f;

#define PROC(S) do {                                                        \
        const uint2 raw = *(const uint2*)(xl + (size_t)(S) * HID + f0);     \
        const float m0 = u2f(raw.x << 16);                                  \
        const float m1 = u2f(raw.x & 0xffff0000u);                          \
        const float m2 = u2f(raw.y << 16);                                  \
        const float m3 = u2f(raw.y & 0xffff0000u);                          \
        const float t0 = m0 + xrv.x;                                        \
        const float t1 = m1 + xrv.y;                                        \
        const float t2 = m2 + xrv.z;                                        \
        const float t3 = m3 + xrv.w;                                        \
        float v = t0 * a06.x + fabsf(t0) * a04.x                            \
                + t1 * a06.y + fabsf(t1) * a04.y                            \
                + t2 * a06.z + fabsf(t2) * a04.z                            \
                + t3 * a06.w + fabsf(t3) * a04.w;                           \
        v += __shfl_xor(v, 1);                                              \
        v += __shfl_xor(v, 2);                                              \
        v += __shfl_xor(v, 4);                                              \
        const float a = __expf(v);                                          \
        z += a;                                                             \
        acc.x += a * m0; acc.y += a * m1; acc.z += a * m2; acc.w += a * m3; \
    } while (0)

    int sbuf = (lane32 < deg) ? esrc[beg + lane32] : 0;
    int i = 0;
    while (true) {
        const int lim = min(deg, (i & ~31) + 32);
        for (; i + 2 <= lim; i += 2) {
            const int s0 = __shfl(sbuf, gbase + (i & 31));
            const int s1 = __shfl(sbuf, gbase + ((i + 1) & 31));
            PROC(s0);
            PROC(s1);
        }
        if (i < lim) {
            const int s0 = __shfl(sbuf, gbase + (i & 31));
            PROC(s0);
            i++;
        }
        if (i >= deg) break;
        sbuf = (i + lane32 < deg) ? esrc[beg + i + lane32] : 0;
    }
#undef PROC

    const float inv = 1.f / z;
    const float ox = acc.x * inv, oy = acc.y * inv, oz = acc.z * inv, ow = acc.w * inv;

    float s1 = ox + oy + oz + ow;
    float s2 = ox * ox + oy * oy + oz * oz + ow * ow;
#pragma unroll
    for (int off = 1; off < 32; off <<= 1) {
        s1 += __shfl_xor(s1, off);
        s2 += __shfl_xor(s2, off);
    }
    const float mu = s1 / (float)HID;
    const float rstd = rsqrtf(s2 / (float)HID - mu * mu + LN_EPS);
    const float4 gv = *(const float4*)(g + f0);
    const float4 bv = *(const float4*)(b + f0);
    float nx = (ox - mu) * rstd * gv.x + bv.x;
    float ny = (oy - mu) * rstd * gv.y + bv.y;
    float nz = (oz - mu) * rstd * gv.z + bv.z;
    float nw = (ow - mu) * rstd * gv.w + bv.w;
    nx = nx > 0.f ? nx : expm1f(nx);
    ny = ny > 0.f ? ny : expm1f(ny);
    nz = nz > 0.f ? nz : expm1f(nz);
    nw = nw > 0.f ? nw : expm1f(nw);
    const float4 hv = *(const float4*)(hres + (size_t)node * HID + f0);
    float4 res;
    res.x = hv.x + nx; res.y = hv.y + ny; res.z = hv.z + nz; res.w = hv.w + nw;
    *(float4*)(dest + (size_t)node * HID + f0) = res;
    if (destb) {
        unsigned short* db = destb + (size_t)node * HID + f0;
        db[0] = f2bf(res.x); db[1] = f2bf(res.y);
        db[2] = f2bf(res.z); db[3] = f2bf(res.w);
    }
}

extern "C" void kernel_launch(void* const* d_in, const int* in_sizes, int n_in,
                              void* d_out, int out_size, void* d_ws, size_t ws_size,
                              hipStream_t stream) {
    const float* x       = (const float*)d_in[0];
    const float* W_in    = (const float*)d_in[1];
    const float* b_in    = (const float*)d_in[2];
    const float* ln_in_g = (const float*)d_in[3];
    const float* ln_in_b = (const float*)d_in[4];
    const float* Wl      = (const float*)d_in[5];
    const float* Wr      = (const float*)d_in[6];
    const float* att     = (const float*)d_in[7];
    const float* ln_g    = (const float*)d_in[8];
    const float* ln_b    = (const float*)d_in[9];
    const int*   ei      = (const int*)d_in[10];
    float* out = (float*)d_out;

    float* h  = (float*)d_ws;                                  // NN*128 f32
    float* xr = h + (size_t)NN * HID;                          // NN*128 f32
    unsigned short* hb  = (unsigned short*)(xr + (size_t)NN * HID);   // NN*128 bf16
    unsigned short* xlb = hb + (size_t)NN * HID;               // NN*128 bf16
    float4* wp = (float4*)(xlb + (size_t)NN * HID);            // 12288 slots
    int* cnt    = (int*)(wp + 12288);
    int* fill   = cnt + NN;
    int* rowptr = fill + NN;
    int* bsum   = rowptr + (NN + 1);
    int* bpre   = bsum + NB;
    int* esrc   = bpre + NB;

    prep_weights<<<48, 256, 0, stream>>>(W_in, Wl, Wr, wp);

    hipMemsetAsync(cnt, 0, 2 * NN * sizeof(int), stream);
    const int eblocks = (EP + 255) / 256;
    dst_hist<<<eblocks, 256, 0, stream>>>(ei, cnt);
    scan_bsum<<<NB, 256, 0, stream>>>(cnt, bsum);
    scan_bpre<<<1, 256, 0, stream>>>(bsum, bpre);
    scan_rowptr<<<NB, 256, 0, stream>>>(cnt, bpre, rowptr);
    csr_scatter<<<eblocks, 256, 0, stream>>>(ei, rowptr, fill, esrc);

    const int mblocks = (NN + 63) / 64;
    gemm_in_mfma<<<mblocks, 256, 0, stream>>>(x, wp, b_in, ln_in_g, ln_in_b, h, hb);

    for (int l = 0; l < 2; l++) {
        gemm_xlxr_mfma<<<mblocks, 256, 0, stream>>>(hb, wp + 4096 + l * 4096, xlb, xr);
        gat_ln<<<(NN + 7) / 8, 256, 0, stream>>>(xlb, xr, att + (size_t)l * HID,
                                                 rowptr, esrc,
                                                 ln_g + (size_t)l * HID,
                                                 ln_b + (size_t)l * HID,
                                                 h, (l == 0) ? h : out,
                                                 (l == 0) ? hb : (unsigned short*)nullptr);
    }
}